// Round 4
// baseline (209.717 us; speedup 1.0000x reference)
//
#include <hip/hip_runtime.h>

#define SLOT 24   // fixed slots per node; Poisson(8) P(deg>24) ~ 1e-7 -> overflow list ~empty

// ============ Slot-CSR fill: lean kernel, max occupancy, 4 edges/thread ILP ============
__global__ __launch_bounds__(256) void k_fill(
    const int* __restrict__ src, const int* __restrict__ dst,
    int* __restrict__ cnt, int* __restrict__ slots,
    int* __restrict__ ovf_n, int* __restrict__ ovf_dst, int* __restrict__ ovf_src,
    int n_edges)
{
    const int e0 = (blockIdx.x * 256 + threadIdx.x) * 4;
    if (e0 >= n_edges) return;
    int d[4], sr[4];
    int ne = 4;
    if (e0 + 3 < n_edges) {
        const int4 dv = *(const int4*)(dst + e0);
        const int4 sv = *(const int4*)(src + e0);
        d[0] = dv.x; d[1] = dv.y; d[2] = dv.z; d[3] = dv.w;
        sr[0] = sv.x; sr[1] = sv.y; sr[2] = sv.z; sr[3] = sv.w;
    } else {
        ne = n_edges - e0;
        for (int k = 0; k < ne; ++k) { d[k] = dst[e0 + k]; sr[k] = src[e0 + k]; }
    }
#pragma unroll
    for (int k = 0; k < 4; ++k) {
        if (k >= ne) break;
        const int pos = atomicAdd(&cnt[d[k]], 1);
        if (pos < SLOT) {
            slots[(size_t)d[k] * SLOT + pos] = sr[k];
        } else {   // exact fallback, expected never
            const int op = atomicAdd(ovf_n, 1);
            ovf_dst[op] = d[k];
            ovf_src[op] = sr[k];
        }
    }
}

// ============ Transform1: p1 = x@W1rel, r1 = x@W1root + b1 (64->16), 64 nodes/block ====
__global__ __launch_bounds__(256) void k_transform1(
    const float* __restrict__ x, const float* __restrict__ Wrel,
    const float* __restrict__ Wroot, const float* __restrict__ bias,
    float* __restrict__ p1, float* __restrict__ r1, int n_nodes)
{
    __shared__ float s_x[64 * 68];      // pad 64->68
    __shared__ float s_wrT[16 * 68];    // transposed [o][k], padded
    __shared__ float s_woT[16 * 68];
    __shared__ float s_b[16];

    const int t = threadIdx.x;
    for (int i = t; i < 1024; i += 256) {
        const int k = i >> 4, o = i & 15;
        s_wrT[o * 68 + k] = Wrel[i];
        s_woT[o * 68 + k] = Wroot[i];
    }
    if (t < 16) s_b[t] = bias[t];

    const int node0 = blockIdx.x * 64;
    for (int i = t; i < 1024; i += 256) {   // 64 rows x 16 float4, coalesced
        const int r = i >> 4, c = i & 15;
        const int node = node0 + r;
        if (node < n_nodes)
            *(float4*)&s_x[r * 68 + c * 4] =
                *(const float4*)(x + (size_t)node * 64 + c * 4);
    }
    __syncthreads();

    const int o = t & 15, ng = t >> 4;
    float accr[4] = {0.f, 0.f, 0.f, 0.f};
    float acco[4] = {0.f, 0.f, 0.f, 0.f};
#pragma unroll
    for (int k4 = 0; k4 < 16; ++k4) {
        const float4 wr = *(const float4*)&s_wrT[o * 68 + k4 * 4];
        const float4 wo = *(const float4*)&s_woT[o * 68 + k4 * 4];
#pragma unroll
        for (int j = 0; j < 4; ++j) {
            const float4 xv = *(const float4*)&s_x[(ng * 4 + j) * 68 + k4 * 4];
            accr[j] = fmaf(xv.x, wr.x, fmaf(xv.y, wr.y, fmaf(xv.z, wr.z, fmaf(xv.w, wr.w, accr[j]))));
            acco[j] = fmaf(xv.x, wo.x, fmaf(xv.y, wo.y, fmaf(xv.z, wo.z, fmaf(xv.w, wo.w, acco[j]))));
        }
    }
#pragma unroll
    for (int j = 0; j < 4; ++j) {
        const int node = node0 + ng * 4 + j;
        if (node < n_nodes) {
            p1[(size_t)node * 16 + o] = accr[j];   // lane-contiguous over o: coalesced
            r1[(size_t)node * 16 + o] = acco[j] + s_b[o];
        }
    }
}

// ============ Gather + relu + folded layer-2 scalars + per-graph u/count bins ============
// 4 threads per node (q = float4 quarter). s[i]=relu(h1)@w2r ; T2 bins += relu(h1)@w2o
__global__ __launch_bounds__(256) void k_gather(
    const float* __restrict__ p1, const float* __restrict__ r1,
    const int* __restrict__ cnt, const int* __restrict__ slots,
    const int* __restrict__ ovf_n, const int* __restrict__ ovf_dst,
    const int* __restrict__ ovf_src,
    const int* __restrict__ batch,
    const float* __restrict__ W2rel, const float* __restrict__ W2root,
    const float* __restrict__ Wlin,
    float* __restrict__ s_out, float* __restrict__ T2, float* __restrict__ cntg,
    int n_nodes)
{
    __shared__ float s_w2r[16], s_w2o[16];
    __shared__ float s_T2[64], s_cnt[64];
    __shared__ int s_no;

    const int t = threadIdx.x;
    if (t < 16) {   // fold W2 through the linear head
        float ar = 0.f, ao = 0.f;
#pragma unroll
        for (int o = 0; o < 16; ++o) {
            const float wl = Wlin[o];
            ar = fmaf(W2rel[t * 16 + o], wl, ar);
            ao = fmaf(W2root[t * 16 + o], wl, ao);
        }
        s_w2r[t] = ar; s_w2o[t] = ao;
    }
    if (t < 64) { s_T2[t] = 0.f; s_cnt[t] = 0.f; }
    if (t == 0) s_no = *ovf_n;
    __syncthreads();

    const int idx = blockIdx.x * 256 + t;
    const int node = idx >> 2, q = idx & 3;
    if (node < n_nodes) {
        float4 h = *(const float4*)(r1 + (size_t)node * 16 + q * 4);
        const int c = min(cnt[node], SLOT);
        const int base = node * SLOT;   // 96 B row -> 16B-aligned
        int j = 0;
        for (; j + 4 <= c; j += 4) {    // one int4 index load feeds 4 independent gathers
            const int4 s4 = *(const int4*)&slots[base + j];
            const float4 a = *(const float4*)(p1 + (size_t)s4.x * 16 + q * 4);
            const float4 b = *(const float4*)(p1 + (size_t)s4.y * 16 + q * 4);
            const float4 cc = *(const float4*)(p1 + (size_t)s4.z * 16 + q * 4);
            const float4 dd = *(const float4*)(p1 + (size_t)s4.w * 16 + q * 4);
            h.x += a.x + b.x + cc.x + dd.x;
            h.y += a.y + b.y + cc.y + dd.y;
            h.z += a.z + b.z + cc.z + dd.z;
            h.w += a.w + b.w + cc.w + dd.w;
        }
        for (; j < c; ++j) {
            const int s0 = slots[base + j];
            const float4 a = *(const float4*)(p1 + (size_t)s0 * 16 + q * 4);
            h.x += a.x; h.y += a.y; h.z += a.z; h.w += a.w;
        }
        for (int ov = 0; ov < s_no; ++ov) {   // overflow list (expected empty)
            if (ovf_dst[ov] == node) {
                const float4 a = *(const float4*)(p1 + (size_t)ovf_src[ov] * 16 + q * 4);
                h.x += a.x; h.y += a.y; h.z += a.z; h.w += a.w;
            }
        }
        h.x = fmaxf(h.x, 0.f); h.y = fmaxf(h.y, 0.f);
        h.z = fmaxf(h.z, 0.f); h.w = fmaxf(h.w, 0.f);
        const float4 wr = *(const float4*)&s_w2r[q * 4];
        const float4 wo = *(const float4*)&s_w2o[q * 4];
        float ps = h.x * wr.x + h.y * wr.y + h.z * wr.z + h.w * wr.w;
        float pu = h.x * wo.x + h.y * wo.y + h.z * wo.z + h.w * wo.w;
        ps += __shfl_xor(ps, 1); ps += __shfl_xor(ps, 2);
        pu += __shfl_xor(pu, 1); pu += __shfl_xor(pu, 2);
        if (q == 0) {
            s_out[node] = ps;
            const int g = batch[node];
            atomicAdd(&s_T2[g], pu);
            atomicAdd(&s_cnt[g], 1.f);
        }
    }
    __syncthreads();
    if (t < 64) {
        if (s_T2[t] != 0.f) atomicAdd(&T2[t], s_T2[t]);
        if (s_cnt[t] != 0.f) atomicAdd(&cntg[t], s_cnt[t]);
    }
}

// ============ Edge pass: T1[batch[dst]] += s[src], LDS-privatized, 4 edges/thread ============
__global__ __launch_bounds__(256) void k_edgeT1(
    const int* __restrict__ src, const int* __restrict__ dst,
    const int* __restrict__ batch, const float* __restrict__ s_in,
    float* __restrict__ T1, int n_edges)
{
    __shared__ float bins[64];
    const int t = threadIdx.x;
    if (t < 64) bins[t] = 0.f;
    __syncthreads();

    const int e0 = (blockIdx.x * 256 + t) * 4;
    if (e0 < n_edges) {
        int d[4], sr[4];
        int ne = 4;
        if (e0 + 3 < n_edges) {
            const int4 dv = *(const int4*)(dst + e0);
            const int4 sv = *(const int4*)(src + e0);
            d[0] = dv.x; d[1] = dv.y; d[2] = dv.z; d[3] = dv.w;
            sr[0] = sv.x; sr[1] = sv.y; sr[2] = sv.z; sr[3] = sv.w;
        } else {
            ne = n_edges - e0;
            for (int k = 0; k < ne; ++k) { d[k] = dst[e0 + k]; sr[k] = src[e0 + k]; }
        }
        int g[4]; float v[4];
#pragma unroll
        for (int k = 0; k < 4; ++k) {
            if (k >= ne) break;
            g[k] = batch[d[k]];
            v[k] = s_in[sr[k]];
        }
#pragma unroll
        for (int k = 0; k < 4; ++k) {
            if (k >= ne) break;
            atomicAdd(&bins[g[k]], v[k]);
        }
    }
    __syncthreads();
    if (t < 64 && bins[t] != 0.f) atomicAdd(&T1[t], bins[t]);
}

// ============ Head: out[g] = (T1+T2)/c + b2.Wlin + blin ============
__global__ void k_finalize(
    const float* __restrict__ T1, const float* __restrict__ T2,
    const float* __restrict__ cntg, const float* __restrict__ b2,
    const float* __restrict__ Wlin, const float* __restrict__ blin,
    float* __restrict__ out, int n_graphs)
{
    const int g = threadIdx.x;
    if (g >= n_graphs) return;
    float cb = 0.f;
#pragma unroll
    for (int o = 0; o < 16; ++o) cb = fmaf(b2[o], Wlin[o], cb);
    const float c = fmaxf(cntg[g], 1.f);
    out[g] = (T1[g] + T2[g]) / c + cb + blin[0];
}

extern "C" void kernel_launch(void* const* d_in, const int* in_sizes, int n_in,
                              void* d_out, int out_size, void* d_ws, size_t ws_size,
                              hipStream_t stream) {
    const float* x       = (const float*)d_in[0];
    const int*   ei      = (const int*)d_in[1];
    const int*   batch   = (const int*)d_in[2];
    const float* W1_rel  = (const float*)d_in[3];
    const float* W1_root = (const float*)d_in[4];
    const float* b1      = (const float*)d_in[5];
    const float* W2_rel  = (const float*)d_in[6];
    const float* W2_root = (const float*)d_in[7];
    const float* b2      = (const float*)d_in[8];
    const float* Wlin    = (const float*)d_in[9];
    const float* blin    = (const float*)d_in[10];
    float* out = (float*)d_out;

    const int N = in_sizes[0] / 64;
    const int E = in_sizes[1] / 2;
    const int G = out_size;

    const int* src = ei;
    const int* dst = ei + E;

    // ---- workspace layout (slots 16B-aligned: offset 32N floats; SLOT*4=96B rows) ----
    float* ws      = (float*)d_ws;
    float* p1      = ws;                               // N*16
    float* r1      = p1 + (size_t)N * 16;              // N*16
    int*   slots   = (int*)(r1 + (size_t)N * 16);      // N*SLOT
    int*   cnt     = slots + (size_t)N * SLOT;         // N      -- memset start
    int*   ovf_n   = cnt + N;                          // 1
    float* T1      = (float*)(ovf_n + 1);              // G
    float* T2      = T1 + G;                           // G
    float* cntg    = T2 + G;                           // G      -- memset end
    int*   ovf_dst = (int*)(cntg + G);                 // E
    int*   ovf_src = ovf_dst + E;                      // E
    float* s_buf   = (float*)(ovf_src + E);            // N

    hipMemsetAsync(cnt, 0, (size_t)(N + 1 + 3 * G) * sizeof(int), stream);

    const int fb  = (E + 1023) / 1024;       // fill blocks (4 edges/thread)
    const int tb  = (N + 63) / 64;           // transform blocks
    const int gb  = (N * 4 + 255) / 256;     // gather blocks
    const int ebt = (E + 1023) / 1024;       // edgeT1 blocks

    k_fill      <<<fb, 256, 0, stream>>>(src, dst, cnt, slots, ovf_n, ovf_dst, ovf_src, E);
    k_transform1<<<tb, 256, 0, stream>>>(x, W1_rel, W1_root, b1, p1, r1, N);
    k_gather    <<<gb, 256, 0, stream>>>(p1, r1, cnt, slots, ovf_n, ovf_dst, ovf_src,
                                         batch, W2_rel, W2_root, Wlin,
                                         s_buf, T2, cntg, N);
    k_edgeT1    <<<ebt, 256, 0, stream>>>(src, dst, batch, s_buf, T1, E);
    k_finalize  <<<1, 64, 0, stream>>>(T1, T2, cntg, b2, Wlin, blin, out, G);
}